// Round 11
// baseline (152.526 us; speedup 1.0000x reference)
//
#include <hip/hip_runtime.h>
#include <math.h>

#define EPS_N 1e-12f
#define MARGIN 0.3f
#define INF_BITS 0x7f800000u
#define NCLS 128     // label space (randint(0,128))
#define D 512
#define PADR 256     // padded rows after fh8 (safety margin)

typedef __attribute__((ext_vector_type(8))) char  char8;    // 8 i8 = 8 B
typedef __attribute__((ext_vector_type(4))) int   int4x;    // i8-MFMA A/B/acc (4 VGPR)

__device__ __forceinline__ void gl16(const void* g, void* l) {
    // 16B async global->LDS; global addr per-lane, LDS dest = uniform base + lane*16
    __builtin_amdgcn_global_load_lds((const __attribute__((address_space(1))) void*)g,
                                     (__attribute__((address_space(3))) void*)l, 16, 0, 0);
}

// ---------------------------------------------------------------------------
// K0 (R22): one-block bucketing. Binary-search metadata pass REMOVED — all
// per-slot metadata is written in the scatter loop at the slot index the
// atomicAdd returns (per-class 1/m precomputed once: 128 divides, not 8192).
// ---------------------------------------------------------------------------
__global__ __launch_bounds__(1024) void k_bucket(const int* __restrict__ lab, int Bn,
        int* __restrict__ pos, int* __restrict__ labp,
        int* __restrict__ cstart_g, int* __restrict__ ccnt_g,
        float* __restrict__ meanpos, float* __restrict__ pcinv,
        int* __restrict__ poscnt, unsigned* __restrict__ minbits) {
    __shared__ int cnt[NCLS], off[NCLS], sa[NCLS], sb[NCLS];
    __shared__ float cinv[NCLS];
    int tid = threadIdx.x;
    if (tid < NCLS) cnt[tid] = 0;
    __syncthreads();
    for (int i = tid; i < Bn; i += 1024) atomicAdd(&cnt[lab[i] & (NCLS - 1)], 1);
    __syncthreads();
    if (tid < NCLS) sa[tid] = cnt[tid];
    __syncthreads();
    int* src = sa; int* dst = sb;
    for (int ofs = 1; ofs < NCLS; ofs <<= 1) {          // Hillis-Steele inclusive
        if (tid < NCLS) dst[tid] = src[tid] + ((tid >= ofs) ? src[tid - ofs] : 0);
        __syncthreads();
        int* t = src; src = dst; dst = t;
    }
    if (tid < NCLS) {
        int ex = src[tid] - cnt[tid];                   // exclusive
        off[tid] = ex;
        cstart_g[tid] = ex;
        ccnt_g[tid] = cnt[tid];
        cinv[tid] = 1.0f / (float)cnt[tid];
    }
    __syncthreads();
    // scatter + fused per-slot metadata (reads coalesced; stores scattered)
    for (int i = tid; i < Bn; i += 1024) {
        int l = lab[i] & (NCLS - 1);
        int pp = atomicAdd(&off[l], 1);
        pos[i] = pp;
        labp[pp] = l;
        poscnt[pp] = cnt[l];
        pcinv[pp] = cinv[l];
        meanpos[pp] = 0.f;
        minbits[pp] = INF_BITS;
    }
}

// ---------------------------------------------------------------------------
// K1: normalize + per-row symmetric i8 quantization (unchanged from R21).
// ---------------------------------------------------------------------------
__global__ __launch_bounds__(256) void k_normalize(const float* __restrict__ x,
        const int* __restrict__ pos, char* __restrict__ fh8,
        float* __restrict__ qs, float* __restrict__ sqp) {
    int w = threadIdx.x >> 6, L = threadIdx.x & 63;
    int row = blockIdx.x * 4 + w;
    const float* xr = x + (size_t)row * D + L * 8;
    float4 a = *(const float4*)xr;
    float4 b = *(const float4*)(xr + 4);
    float ss = a.x * a.x;
    ss = fmaf(a.y, a.y, ss); ss = fmaf(a.z, a.z, ss); ss = fmaf(a.w, a.w, ss);
    ss = fmaf(b.x, b.x, ss); ss = fmaf(b.y, b.y, ss);
    ss = fmaf(b.z, b.z, ss); ss = fmaf(b.w, b.w, ss);
    #pragma unroll
    for (int off = 32; off; off >>= 1) ss += __shfl_xor(ss, off, 64);
    float inv = 1.0f / fmaxf(sqrtf(ss), EPS_N);
    float e0 = a.x * inv, e1 = a.y * inv, e2 = a.z * inv, e3 = a.w * inv;
    float e4 = b.x * inv, e5 = b.y * inv, e6 = b.z * inv, e7 = b.w * inv;
    float mv = fmaxf(fmaxf(fmaxf(fabsf(e0), fabsf(e1)), fmaxf(fabsf(e2), fabsf(e3))),
                     fmaxf(fmaxf(fabsf(e4), fabsf(e5)), fmaxf(fabsf(e6), fabsf(e7))));
    #pragma unroll
    for (int off = 32; off; off >>= 1) mv = fmaxf(mv, __shfl_xor(mv, off, 64));
    float r127 = 127.0f / mv;
    int prow = pos[row];
    if (L == 0) {
        sqp[prow] = ss * inv * inv;      // ~1.0 (exact norm of fp32 normalize)
        qs[prow]  = mv * (1.0f / 127.0f);
    }
    char8 pk;
    pk[0] = (char)__float2int_rn(e0 * r127);
    pk[1] = (char)__float2int_rn(e1 * r127);
    pk[2] = (char)__float2int_rn(e2 * r127);
    pk[3] = (char)__float2int_rn(e3 * r127);
    pk[4] = (char)__float2int_rn(e4 * r127);
    pk[5] = (char)__float2int_rn(e5 * r127);
    pk[6] = (char)__float2int_rn(e6 * r127);
    pk[7] = (char)__float2int_rn(e7 * r127);
    *(char8*)(fh8 + (size_t)prow * D + L * 8) = pk;
}

// ---------------------------------------------------------------------------
// K2: per-class positive stats, i8 (unchanged from R21; measured-good).
// ---------------------------------------------------------------------------
__global__ __launch_bounds__(256) void k_posclass(
    const char* __restrict__ fh8, const float* __restrict__ sqp,
    const float* __restrict__ qs, const int* __restrict__ cstart_g,
    const int* __restrict__ ccnt_g, float* __restrict__ meanpos)
{
    const int c = blockIdx.x;
    const int s = cstart_g[c], n = ccnt_g[c];
    if (n <= 1) return;                         // no positives; meanpos stays 0

    __shared__ char SA[128 * 128];              // row chunk [r][K128] 16 KB
    __shared__ char SB[128 * 128];              // col chunk 16 KB
    __shared__ float sqr_sh[128], sqs[128], rs[128], qsr_sh[128], qss[128];

    const int tid = threadIdx.x, w = tid >> 6, L = tid & 63;
    const int lm = L & 15, ls = L >> 4;

    for (int rb = 0; rb < n; rb += 128) {
        const int nr = min(128, n - rb);
        __syncthreads();
        if (tid < 128) {
            rs[tid] = 0.f;
            sqr_sh[tid] = (tid < nr) ? sqp[s + rb + tid] : 0.f;
            qsr_sh[tid] = (tid < nr) ? qs[s + rb + tid] : 0.f;
        }
        for (int cb = 0; cb < n; cb += 128) {
            const int m = min(128, n - cb);
            const bool same = (rb == cb);
            __syncthreads();                    // prior epilogue done
            if (tid < 128) {
                sqs[tid] = (tid < m) ? sqp[s + cb + tid] : 0.f;
                qss[tid] = (tid < m) ? qs[s + cb + tid] : 0.f;
            }

            int4x acc[8][2];
            #pragma unroll
            for (int rt = 0; rt < 8; ++rt)
                #pragma unroll
                for (int ct = 0; ct < 2; ++ct) acc[rt][ct] = (int4x){0, 0, 0, 0};

            for (int k0 = 0; k0 < D; k0 += 128) {   // 4 chunks of 128 i8
                __syncthreads();                // prev MFMA reads done
                #pragma unroll
                for (int q = 0; q < 4; ++q) {   // 1024 16B slots (128 rows x 8)
                    int slot = tid + 256 * q;
                    int r = slot >> 3;
                    int u = (slot & 7) ^ (r & 7);   // pre-swizzled global seg
                    if (r < nr)
                        gl16(fh8 + (size_t)(s + rb + r) * D + k0 + u * 16,
                             &SA[(size_t)slot * 16]);
                }
                if (!same) {
                    #pragma unroll
                    for (int q = 0; q < 4; ++q) {
                        int slot = tid + 256 * q;
                        int r = slot >> 3;
                        int u = (slot & 7) ^ (r & 7);
                        if (r < m)
                            gl16(fh8 + (size_t)(s + cb + r) * D + k0 + u * 16,
                                 &SB[(size_t)slot * 16]);
                    }
                }
                __syncthreads();                // drains vmcnt: chunk landed
                const char* Bb = same ? SA : SB;
                #pragma unroll
                for (int h = 0; h < 2; ++h) {   // K=128 in 2 i8-MFMA sub-steps
                    int4x bf[2];
                    #pragma unroll
                    for (int ct = 0; ct < 2; ++ct) {
                        int cr = w * 32 + ct * 16 + lm;
                        bf[ct] = *(const int4x*)&Bb[cr * 128 + (((h * 4 + ls) ^ (cr & 7))) * 16];
                    }
                    #pragma unroll
                    for (int rt = 0; rt < 8; ++rt) {
                        int ar = rt * 16 + lm;
                        int4x af = *(const int4x*)&SA[ar * 128 + (((h * 4 + ls) ^ (ar & 7))) * 16];
                        #pragma unroll
                        for (int ct = 0; ct < 2; ++ct)
                            acc[rt][ct] = __builtin_amdgcn_mfma_i32_16x16x64_i8(af, bf[ct], acc[rt][ct], 0, 0, 0);
                    }
                }
            }
            // epilogue: masked dist row-sums. C/D: row = rt*16+ls*4+v, col = w*32+ct*16+lm
            #pragma unroll
            for (int rt = 0; rt < 8; ++rt) {
                #pragma unroll
                for (int v = 0; v < 4; ++v) {
                    int ri = rt * 16 + ls * 4 + v;
                    float sr = sqr_sh[ri];
                    float qr = qsr_sh[ri];
                    float sum = 0.f;
                    #pragma unroll
                    for (int ct = 0; ct < 2; ++ct) {
                        int ci = w * 32 + ct * 16 + lm;
                        float dot = (float)acc[rt][ct][v] * qr * qss[ci];
                        float d2 = sr + sqs[ci] - 2.0f * dot;
                        bool ok = (ri < nr) && (ci < m) && (rb + ri != cb + ci) && (d2 > 0.f);
                        sum += ok ? sqrtf(d2) : 0.f;
                    }
                    #pragma unroll
                    for (int off = 8; off; off >>= 1) sum += __shfl_xor(sum, off, 64);
                    if (lm == 0 && sum != 0.f) atomicAdd(&rs[ri], sum);
                }
            }
        }
        __syncthreads();
        if (tid < nr) meanpos[s + rb + tid] = rs[tid];   // single writer
    }
}

// ---------------------------------------------------------------------------
// K3: i8 R8-structure (R21, measured 48 us) + LDS-combined min epilogue:
// row/col mins accumulate in LDS (LA is dead after the K-loop — reuse), then
// <=256 INF-filtered global atomicMin per block instead of 512 device-scope
// atomics. Loop body unchanged.
// ---------------------------------------------------------------------------
__global__ __launch_bounds__(256, 4) void k_minsh_mfma(
    const char* __restrict__ fh8, const float* __restrict__ sqp,
    const float* __restrict__ qs, const int* __restrict__ labp,
    const float* __restrict__ meanpos, const float* __restrict__ pcinv,
    unsigned* __restrict__ minbits)
{
    int t = (blockIdx.x & 7) * 260 + (blockIdx.x >> 3);   // XCD-bijective
    int rq = (int)((sqrtf(8.0f * (float)t + 1.0f) - 1.0f) * 0.5f);
    while ((rq + 1) * (rq + 2) / 2 <= t) ++rq;
    while (rq * (rq + 1) / 2 > t) --rq;
    int cq = t - rq * (rq + 1) / 2;
    const int i0 = cq * 128, j0 = rq * 128;
    const bool diag = (i0 == j0);

    __shared__ char LA[2][128 * 128];             // 32 KB (two 16-KB tiles)
    __shared__ float s_mp2r[128], s_mp2c[128], s_sqr[128], s_sqc[128];
    __shared__ float s_qsr[128], s_qsc[128];
    __shared__ int s_labr[128], s_labc[128];

    const int tid = threadIdx.x;
    const int w = tid >> 6, L = tid & 63;

    if (tid < 128) {
        float mp = meanpos[i0 + tid] * pcinv[i0 + tid];
        s_mp2r[tid] = mp * mp;
        s_sqr[tid]  = sqp[i0 + tid];
        s_qsr[tid]  = qs[i0 + tid];
        s_labr[tid] = labp[i0 + tid];
    } else {
        int q = tid - 128;
        float mp = meanpos[j0 + q] * pcinv[j0 + q];
        s_mp2c[q] = mp * mp;
        s_sqc[q]  = sqp[j0 + q];
        s_qsc[q]  = qs[j0 + q];
        s_labc[q] = labp[j0 + q];
    }

    const char* msrc = fh8 + (size_t)((w < 2) ? i0 : j0) * D;
    char* mylds = &LA[(w < 2) ? 0 : 1][(w & 1) * 64 * 128];
    const int srow = L >> 3;
    const int sseg = L & 7;

    int4x acc[4][4];
    #pragma unroll
    for (int a = 0; a < 4; ++a)
        #pragma unroll
        for (int bq = 0; bq < 4; ++bq) acc[a][bq] = (int4x){0, 0, 0, 0};

    const int rw = (w >> 1) * 64, cw = (w & 1) * 64;
    const int lm = L & 15, ls = L >> 4;

    for (int k0 = 0; k0 < D; k0 += 128) {         // 4 staging rounds (K=128)
        __syncthreads();
        #pragma unroll
        for (int it = 0; it < 8; ++it) {          // 8 rows x 128 B per it
            int rmat = (w & 1) * 64 + it * 8 + srow;
            int seg = sseg ^ (rmat & 7);
            gl16(msrc + (size_t)rmat * D + k0 + seg * 16, mylds + it * 1024);
        }
        __syncthreads();
        #pragma unroll
        for (int h = 0; h < 2; ++h) {             // 2 x K=64 MFMA sub-steps
            int4x ah[4], bh[4];
            #pragma unroll
            for (int mi = 0; mi < 4; ++mi) {
                int r = rw + mi * 16 + lm;
                int slot = r * 8 + ((h * 4 + ls) ^ (r & 7));
                ah[mi] = *(const int4x*)&LA[0][slot * 16];
            }
            #pragma unroll
            for (int ni = 0; ni < 4; ++ni) {
                int cc = cw + ni * 16 + lm;
                int slot = cc * 8 + ((h * 4 + ls) ^ (cc & 7));
                bh[ni] = *(const int4x*)&LA[1][slot * 16];
            }
            #pragma unroll
            for (int ni = 0; ni < 4; ++ni)
                #pragma unroll
                for (int mi = 0; mi < 4; ++mi)
                    acc[mi][ni] = __builtin_amdgcn_mfma_i32_16x16x64_i8(ah[mi], bh[ni], acc[mi][ni], 0, 0, 0);
        }
    }

    // --- LDS-combined min epilogue. C/D: row = rw+mi*16+ls*4+v, col = cw+ni*16+lm
    unsigned* rminb = (unsigned*)&LA[0][0];       // LA dead; reuse (1 KB)
    unsigned* cminb = rminb + 128;
    __syncthreads();                              // all LDS MFMA reads done
    if (tid < 128) rminb[tid] = INF_BITS;
    else           cminb[tid - 128] = INF_BITS;
    __syncthreads();

    const float INFF = __uint_as_float(INF_BITS);
    float sc[4], mp2c[4], qc[4];
    int lc[4];
    #pragma unroll
    for (int ni = 0; ni < 4; ++ni) {
        int cl = cw + ni * 16 + lm;
        sc[ni]   = s_sqc[cl];
        mp2c[ni] = s_mp2c[cl];
        qc[ni]   = s_qsc[cl];
        lc[ni]   = s_labc[cl];
    }
    float vminc[4];
    #pragma unroll
    for (int ni = 0; ni < 4; ++ni) vminc[ni] = INFF;

    #pragma unroll
    for (int mi = 0; mi < 4; ++mi) {
        #pragma unroll
        for (int v = 0; v < 4; ++v) {
            int rl = rw + mi * 16 + ls * 4 + v;
            float mp2r = s_mp2r[rl];
            float sr   = s_sqr[rl];
            float qr   = s_qsr[rl];
            int   li   = s_labr[rl];
            float vminr = INFF;
            #pragma unroll
            for (int ni = 0; ni < 4; ++ni) {
                float dot = (float)acc[mi][ni][v] * qr * qc[ni];
                float d2 = fmaf(-2.0f, dot, sr + sc[ni]);
                bool neq = (li != lc[ni]);
                vminr     = fminf(vminr,     (neq && d2 > mp2r)     ? d2 : INFF);
                vminc[ni] = fminf(vminc[ni], (neq && d2 > mp2c[ni]) ? d2 : INFF);
            }
            #pragma unroll
            for (int off = 8; off; off >>= 1)
                vminr = fminf(vminr, __shfl_xor(vminr, off, 64));
            if (lm == 0 && __float_as_uint(vminr) != INF_BITS)
                atomicMin(&rminb[rl], __float_as_uint(vminr));
        }
    }
    if (!diag) {
        #pragma unroll
        for (int ni = 0; ni < 4; ++ni) {
            float vc = vminc[ni];
            vc = fminf(vc, __shfl_xor(vc, 16, 64));
            vc = fminf(vc, __shfl_xor(vc, 32, 64));
            if (ls == 0 && __float_as_uint(vc) != INF_BITS)
                atomicMin(&cminb[cw + ni * 16 + lm], __float_as_uint(vc));
        }
    }
    __syncthreads();
    if (tid < 128) {
        unsigned rb = rminb[tid];
        if (rb != INF_BITS) atomicMin(&minbits[i0 + tid], rb);
    } else if (!diag) {
        unsigned cb = cminb[tid - 128];
        if (cb != INF_BITS) atomicMin(&minbits[j0 + tid - 128], cb);
    }
}

// ---------------------------------------------------------------------------
// K4: final reduction (unchanged).
// ---------------------------------------------------------------------------
__global__ __launch_bounds__(1024) void k_finish(const float* __restrict__ meanpos,
        const float* __restrict__ pcinv, const int* __restrict__ poscnt,
        const unsigned* __restrict__ minbits, float* __restrict__ out, int Bn) {
    float lsum = 0.f; int lcnt = 0;
    for (int i = threadIdx.x; i < Bn; i += 1024) {
        int pc = poscnt[i];
        bool valid = (pc > 1) && (pc < Bn);
        unsigned mb = minbits[i];
        if (valid && mb != INF_BITS) {
            float v = fmaf(meanpos[i], pcinv[i], MARGIN - sqrtf(__uint_as_float(mb)));
            lsum += (v > 0.f) ? v : 0.f;
            lcnt += 1;
        }
    }
    __shared__ float ssum[16]; __shared__ int scnt[16];
    int lane = threadIdx.x & 63, wid = threadIdx.x >> 6;
    #pragma unroll
    for (int off = 32; off; off >>= 1) {
        lsum += __shfl_down(lsum, off, 64);
        lcnt += __shfl_down(lcnt, off, 64);
    }
    if (lane == 0) { ssum[wid] = lsum; scnt[wid] = lcnt; }
    __syncthreads();
    if (threadIdx.x == 0) {
        float s = 0.f; int c = 0;
        #pragma unroll
        for (int q = 0; q < 16; ++q) { s += ssum[q]; c += scnt[q]; }
        out[0] = (c > 0) ? s / (float)c : 0.f;
    }
}

// ---------------------------------------------------------------------------
extern "C" void kernel_launch(void* const* d_in, const int* in_sizes, int n_in,
                              void* d_out, int out_size, void* d_ws, size_t ws_size,
                              hipStream_t stream) {
    const float* x = (const float*)d_in[0];
    const int* lab = (const int*)d_in[1];
    int Bn = in_sizes[1];                 // 8192; D fixed at 512

    size_t nd8 = (size_t)(Bn + PADR) * D; // i8 feature matrix (bytes)
    char* fh8         = (char*)d_ws;
    float* sqp        = (float*)(fh8 + nd8);
    float* qsv        = sqp + Bn;         // per-row dequant scalars
    float* meanpos    = qsv + Bn;         // raw dist-sums
    float* pcinv      = meanpos + Bn;
    int* poscnt       = (int*)(pcinv + Bn);
    unsigned* minbits = (unsigned*)(poscnt + Bn);
    int* pos          = (int*)(minbits + Bn);
    int* labp         = pos + Bn;
    int* cstart_g     = labp + Bn;
    int* ccnt_g       = cstart_g + NCLS;

    k_bucket<<<1, 1024, 0, stream>>>(lab, Bn, pos, labp, cstart_g, ccnt_g,
                                     meanpos, pcinv, poscnt, minbits);
    k_normalize<<<Bn / 4, 256, 0, stream>>>(x, pos, fh8, qsv, sqp);
    k_posclass<<<NCLS, 256, 0, stream>>>(fh8, sqp, qsv, cstart_g, ccnt_g, meanpos);
    int nb = Bn / 128;
    int T = nb * (nb + 1) / 2;            // 2080 = 8*260 (XCD-bijective)
    k_minsh_mfma<<<T, 256, 0, stream>>>(fh8, sqp, qsv, labp, meanpos, pcinv, minbits);
    k_finish<<<1, 1024, 0, stream>>>(meanpos, pcinv, poscnt, minbits,
                                     (float*)d_out, Bn);
}